// Round 7
// baseline (2210.349 us; speedup 1.0000x reference)
//
#include <hip/hip_runtime.h>
#include <cstddef>
#include <cstdint>

// Grouped GRU via MFMA: B=32, C=512, T=2000, G=8, I=64, H=64
// Phase 1 (gru_xproj, all CUs): xp[t] = W_ih x_t + b_ih (+ b_hh for r,z rows),
//   stored f32 in the scan's C-fragment layout (lane-contiguous 12 f32).
// Phase 2 (gru_scan_mfma, 16 blocks): per (g, batch-tile-16) recurrence.
//   Per step/wave: 6x v_mfma_f32_16x16x32_f16 (3 gate-tiles x K=64),
//   h carry f32 in C-layout regs, h^T redistributed via swizzled 4KB LDS.
// T is chunked so xp fits in d_ws; h crosses chunks via h_state in d_ws.

typedef _Float16 f16x8 __attribute__((ext_vector_type(8)));
typedef _Float16 f16x2 __attribute__((ext_vector_type(2)));
typedef float    f32x4 __attribute__((ext_vector_type(4)));

constexpr int B_ = 32, C_ = 512, T_ = 2000, G_ = 8, I_ = 64, H_ = 64, K3_ = 192;
constexpr int GB_ = 16;            // (g, bt) pairs
constexpr int XP_STRIDE = 3072;    // f32 per (gb, t): 192 rows x 16 batches

// LDS-visibility barrier WITHOUT vmcnt drain (global stores/prefetch stay in flight)
#define BARRIER_LGKM() asm volatile("s_waitcnt lgkmcnt(0)\n\ts_barrier" ::: "memory")

__device__ __forceinline__ f32x4 mfma16(f16x8 a, f16x8 b, f32x4 c) {
    return __builtin_amdgcn_mfma_f32_16x16x32_f16(a, b, c, 0, 0, 0);
}

__device__ __forceinline__ f16x8 pack8(float a0,float a1,float a2,float a3,
                                       float a4,float a5,float a6,float a7) {
    auto p0 = __builtin_amdgcn_cvt_pkrtz(a0, a1);   // __fp16x2, 4 bytes
    auto p1 = __builtin_amdgcn_cvt_pkrtz(a2, a3);
    auto p2 = __builtin_amdgcn_cvt_pkrtz(a4, a5);
    auto p3 = __builtin_amdgcn_cvt_pkrtz(a6, a7);
    int4 t; t.x = __builtin_bit_cast(int, p0); t.y = __builtin_bit_cast(int, p1);
            t.z = __builtin_bit_cast(int, p2); t.w = __builtin_bit_cast(int, p3);
    return __builtin_bit_cast(f16x8, t);
}

__device__ __forceinline__ float sigmoid_f(float x) {
    float e = __expf(-x);
    return __builtin_amdgcn_rcpf(1.0f + e);
}
__device__ __forceinline__ float tanh_f(float x) {
    float e = __expf(2.0f * x);               // overflow -> inf -> rcp -> 0 -> 1
    return 1.0f - 2.0f * __builtin_amdgcn_rcpf(e + 1.0f);
}

// ---------------- Phase 1: x-projection into fragment layout ----------------
template <int TC>
__global__ __launch_bounds__(256, 1)
void gru_xproj(const float* __restrict__ x,
               const float* __restrict__ w_ih,
               const float* __restrict__ b_ih,
               const float* __restrict__ b_hh,
               float* __restrict__ xp, int t0, int tlen)
{
    const int gb = blockIdx.y, g = gb >> 1, bt = gb & 1;
    const int tbase = t0 + blockIdx.x * TC;
    const int tid = threadIdx.x;
    const int w = tid >> 6, lw = tid & 63, p = lw >> 4, c = lw & 15;
    const int b_glob = bt * 16 + c;

    // A-frags: W_ih rows 64*mt + 16*w + c; k-map: k = 32*kt + 8*p + e
    f16x8 WI[3][2];
    #pragma unroll
    for (int mt = 0; mt < 3; ++mt) {
        const float* row = w_ih + ((size_t)g * K3_ + 64 * mt + 16 * w + c) * I_;
        #pragma unroll
        for (int kt = 0; kt < 2; ++kt) {
            const float4* p4 = reinterpret_cast<const float4*>(row + 32 * kt + 8 * p);
            float4 A = p4[0], Bq = p4[1];
            WI[mt][kt] = pack8(A.x, A.y, A.z, A.w, Bq.x, Bq.y, Bq.z, Bq.w);
        }
    }
    // Bias C-inits (C row-in-tile = 4p + r): r,z get b_ih+b_hh; n gets b_ih only
    f32x4 biasR, biasZ, biasN;
    #pragma unroll
    for (int r = 0; r < 4; ++r) {
        const int row = 16 * w + 4 * p + r;
        biasR[r] = b_ih[g * K3_ + row]        + b_hh[g * K3_ + row];
        biasZ[r] = b_ih[g * K3_ + 64 + row]   + b_hh[g * K3_ + 64 + row];
        biasN[r] = b_ih[g * K3_ + 128 + row];
    }

    const float* xb = x + ((size_t)b_glob * C_ + g * I_) * T_;   // + q*T_ + t
    float* xpo = xp + ((size_t)gb * tlen + (tbase - t0)) * XP_STRIDE + tid * 12;

    for (int tt = 0; tt < TC / 4; ++tt) {
        // Load x for this lane's 16 k-rows x 4 timesteps (full lines across tt)
        float xq[2][8][4];
        #pragma unroll
        for (int s = 0; s < 2; ++s)
            #pragma unroll
            for (int e = 0; e < 8; ++e) {
                const int q = 32 * s + 8 * p + e;
                float4 v = *reinterpret_cast<const float4*>(xb + (size_t)q * T_ + tbase + tt * 4);
                xq[s][e][0] = v.x; xq[s][e][1] = v.y; xq[s][e][2] = v.z; xq[s][e][3] = v.w;
            }
        #pragma unroll
        for (int tl = 0; tl < 4; ++tl) {
            f16x8 B0 = pack8(xq[0][0][tl], xq[0][1][tl], xq[0][2][tl], xq[0][3][tl],
                             xq[0][4][tl], xq[0][5][tl], xq[0][6][tl], xq[0][7][tl]);
            f16x8 B1 = pack8(xq[1][0][tl], xq[1][1][tl], xq[1][2][tl], xq[1][3][tl],
                             xq[1][4][tl], xq[1][5][tl], xq[1][6][tl], xq[1][7][tl]);
            f32x4 aR = mfma16(WI[0][0], B0, biasR); aR = mfma16(WI[0][1], B1, aR);
            f32x4 aZ = mfma16(WI[1][0], B0, biasZ); aZ = mfma16(WI[1][1], B1, aZ);
            f32x4 aN = mfma16(WI[2][0], B0, biasN); aN = mfma16(WI[2][1], B1, aN);
            float* o = xpo + (size_t)(tt * 4 + tl) * XP_STRIDE;
            *reinterpret_cast<float4*>(o + 0) = make_float4(aR[0], aR[1], aR[2], aR[3]);
            *reinterpret_cast<float4*>(o + 4) = make_float4(aZ[0], aZ[1], aZ[2], aZ[3]);
            *reinterpret_cast<float4*>(o + 8) = make_float4(aN[0], aN[1], aN[2], aN[3]);
        }
    }
}

// ---------------- Phase 2: MFMA scan ----------------
struct XPQ { f32x4 r, z, n; };
__device__ __forceinline__ XPQ ld_xp(const float* base, int tl) {
    const float4* p4 = reinterpret_cast<const float4*>(base + (size_t)tl * XP_STRIDE);
    float4 a = p4[0], b = p4[1], c = p4[2];
    XPQ q;
    q.r = f32x4{a.x, a.y, a.z, a.w};
    q.z = f32x4{b.x, b.y, b.z, b.w};
    q.n = f32x4{c.x, c.y, c.z, c.w};
    return q;
}

__global__ __launch_bounds__(256, 1)
void gru_scan_mfma(const float* __restrict__ xp,
                   const float* __restrict__ h0,
                   const float* __restrict__ w_hh,
                   const float* __restrict__ b_hh,
                   float* __restrict__ out,
                   float* __restrict__ h_state,
                   int t0, int tlen)
{
    const int gb = blockIdx.x, g = gb >> 1, bt = gb & 1;
    const int tid = threadIdx.x;
    const int w = tid >> 6, lw = tid & 63, p = lw >> 4, c = lw & 15;
    const int q0 = 16 * w + 4 * p;
    const int b_glob = bt * 16 + c;

    // h^T planes: halfidx(b=c, q) = c*64 + (q ^ ((c&7)<<3)); uniform bank spread
    __shared__ __align__(16) _Float16 h_lds[2][1024];

    // A-frags: W_hh rows 64*mt + 16*w + c, same k-map as phase 1
    f16x8 WH[3][2];
    #pragma unroll
    for (int mt = 0; mt < 3; ++mt) {
        const float* row = w_hh + ((size_t)g * K3_ + 64 * mt + 16 * w + c) * H_;
        #pragma unroll
        for (int kt = 0; kt < 2; ++kt) {
            const float4* p4 = reinterpret_cast<const float4*>(row + 32 * kt + 8 * p);
            float4 A = p4[0], Bq = p4[1];
            WH[mt][kt] = pack8(A.x, A.y, A.z, A.w, Bq.x, Bq.y, Bq.z, Bq.w);
        }
    }
    f32x4 BHN;   // n-gate C-init = b_hh n-rows
    #pragma unroll
    for (int r = 0; r < 4; ++r) BHN[r] = b_hh[g * K3_ + 128 + q0 + r];

    // h carry (f32, C layout) — from h0 on first chunk, else h_state
    float hC[4];
    if (t0 == 0) {
        #pragma unroll
        for (int r = 0; r < 4; ++r) hC[r] = h0[((size_t)g * B_ + b_glob) * H_ + q0 + r];
    } else {
        #pragma unroll
        for (int r = 0; r < 4; ++r) hC[r] = h_state[gb * 1024 + tid * 4 + r];
    }

    const int swz_w = c * 64 + (q0 ^ ((c & 7) << 3));               // write (4 halves)
    const int rb0 = c * 128 + 16 * ((p)     ^ (c & 7));             // B0 byte offset
    const int rb1 = c * 128 + 16 * ((4 + p) ^ (c & 7));             // B1 byte offset
    {
        f16x2 lo{(_Float16)hC[0], (_Float16)hC[1]};
        f16x2 hi{(_Float16)hC[2], (_Float16)hC[3]};
        int2 v; v.x = __builtin_bit_cast(int, lo); v.y = __builtin_bit_cast(int, hi);
        *reinterpret_cast<int2*>(reinterpret_cast<char*>(&h_lds[0][0]) + 2 * swz_w) = v;
    }

    float* outp = out + ((size_t)b_glob * C_ + g * 64 + q0) * T_;   // + r*T_ + t
    const float* xpl = xp + ((size_t)gb * tlen) * XP_STRIDE + tid * 12;

    // Prefetch depth 2
    XPQ E = ld_xp(xpl, 0);
    XPQ O = ld_xp(xpl, 1);
    __syncthreads();   // publish h_lds[0] (one-time full drain is fine)

    auto STEP = [&](int tl, int rdbuf, const XPQ& xq) {
        char* rbase = reinterpret_cast<char*>(&h_lds[rdbuf][0]);
        f16x8 B0 = *reinterpret_cast<const f16x8*>(rbase + rb0);
        f16x8 B1 = *reinterpret_cast<const f16x8*>(rbase + rb1);
        f32x4 aR = mfma16(WH[0][0], B0, xq.r); aR = mfma16(WH[0][1], B1, aR);
        f32x4 aZ = mfma16(WH[1][0], B0, xq.z); aZ = mfma16(WH[1][1], B1, aZ);
        f32x4 aN = mfma16(WH[2][0], B0, BHN);  aN = mfma16(WH[2][1], B1, aN);
        #pragma unroll
        for (int r = 0; r < 4; ++r) {
            float rr = sigmoid_f(aR[r]);
            float zz = sigmoid_f(aZ[r]);
            float nn = tanh_f(xq.n[r] + rr * aN[r]);
            hC[r] = nn + zz * (hC[r] - nn);
            outp[(size_t)r * T_ + (t0 + tl)] = hC[r];
        }
        f16x2 lo{(_Float16)hC[0], (_Float16)hC[1]};
        f16x2 hi{(_Float16)hC[2], (_Float16)hC[3]};
        int2 v; v.x = __builtin_bit_cast(int, lo); v.y = __builtin_bit_cast(int, hi);
        *reinterpret_cast<int2*>(reinterpret_cast<char*>(&h_lds[rdbuf ^ 1][0]) + 2 * swz_w) = v;
        BARRIER_LGKM();   // LDS visibility only; stores/prefetch stay in flight
    };

    const int half = tlen >> 1;
    for (int it = 0; it < half; ++it) {
        const int tl = 2 * it;
        XPQ nE = ld_xp(xpl, (tl + 2 < tlen) ? tl + 2 : tlen - 1);
        STEP(tl, 0, E);
        XPQ nO = ld_xp(xpl, (tl + 3 < tlen) ? tl + 3 : tlen - 1);
        STEP(tl + 1, 1, O);
        E = nE; O = nO;
    }

    #pragma unroll
    for (int r = 0; r < 4; ++r) h_state[gb * 1024 + tid * 4 + r] = hC[r];
}

// ---------------- Host ----------------
extern "C" void kernel_launch(void* const* d_in, const int* in_sizes, int n_in,
                              void* d_out, int out_size, void* d_ws, size_t ws_size,
                              hipStream_t stream)
{
    const float* x    = (const float*)d_in[0];
    const float* h0   = (const float*)d_in[1];
    const float* w_ih = (const float*)d_in[2];
    const float* w_hh = (const float*)d_in[3];
    const float* b_ih = (const float*)d_in[4];
    const float* b_hh = (const float*)d_in[5];
    float* out = (float*)d_out;

    const size_t HSTATE_BYTES = 65536;
    // (tlen, TC) candidates: tlen | 2000, tlen even, tlen % TC == 0
    const int cand[6][2] = {{400,16},{200,8},{80,16},{40,8},{16,16},{8,8}};
    int tlen = 8, TC = 8;
    for (int i = 0; i < 6; ++i) {
        size_t need = (size_t)cand[i][0] * GB_ * XP_STRIDE * 4 + HSTATE_BYTES;
        if (need <= ws_size) { tlen = cand[i][0]; TC = cand[i][1]; break; }
    }
    float* xp = (float*)d_ws;
    float* h_state = (float*)((char*)d_ws + (size_t)tlen * GB_ * XP_STRIDE * 4);

    for (int t0 = 0; t0 < T_; t0 += tlen) {
        dim3 pg(tlen / TC, GB_);
        if (TC == 16)
            gru_xproj<16><<<pg, 256, 0, stream>>>(x, w_ih, b_ih, b_hh, xp, t0, tlen);
        else
            gru_xproj<8><<<pg, 256, 0, stream>>>(x, w_ih, b_ih, b_hh, xp, t0, tlen);
        gru_scan_mfma<<<GB_, 256, 0, stream>>>(xp, h0, w_hh, b_hh, out, h_state, t0, tlen);
    }
}

// Round 8
// 1214.708 us; speedup vs baseline: 1.8197x; 1.8197x over previous
//
#include <hip/hip_runtime.h>
#include <cstddef>
#include <cstdint>

// Grouped GRU via MFMA: B=32, C=512, T=2000, G=8, I=64, H=64
// Phase 1 (gru_xproj, all CUs): xp[t] = W_ih x_t + b_ih (+ b_hh for r,z rows),
//   stored f32 in the scan's C-fragment layout (lane-contiguous 12 f32).
// Phase 2 (gru_scan_mfma, 16 blocks): per (g, batch-tile-16) recurrence.
//   Per step/wave: 6x v_mfma_f32_16x16x32_f16 (3 gate-tiles x K=64).
// Round-8: output is NOT stored per step (scattered 4B stores serialized the
//   scan through in-order vmcnt retirement). h history kept in registers for
//   16 steps (full unroll -> static indices), flushed as 4x dwordx4 per row
//   (full 64B lines). Per-step vmem chain now contains only xp loads (depth-3
//   prefetch).

typedef _Float16 f16x8 __attribute__((ext_vector_type(8)));
typedef _Float16 f16x2 __attribute__((ext_vector_type(2)));
typedef float    f32x4 __attribute__((ext_vector_type(4)));

constexpr int B_ = 32, C_ = 512, T_ = 2000, G_ = 8, I_ = 64, H_ = 64, K3_ = 192;
constexpr int GB_ = 16;            // (g, bt) pairs
constexpr int XP_STRIDE = 3072;    // f32 per (gb, t): 192 rows x 16 batches
constexpr int FL_ = 16;            // flush group (steps held in registers)

// LDS-visibility barrier WITHOUT vmcnt drain (global stores/prefetch stay in flight)
#define BARRIER_LGKM() asm volatile("s_waitcnt lgkmcnt(0)\n\ts_barrier" ::: "memory")

__device__ __forceinline__ f32x4 mfma16(f16x8 a, f16x8 b, f32x4 c) {
    return __builtin_amdgcn_mfma_f32_16x16x32_f16(a, b, c, 0, 0, 0);
}

__device__ __forceinline__ f16x8 pack8(float a0,float a1,float a2,float a3,
                                       float a4,float a5,float a6,float a7) {
    auto p0 = __builtin_amdgcn_cvt_pkrtz(a0, a1);   // __fp16x2, 4 bytes
    auto p1 = __builtin_amdgcn_cvt_pkrtz(a2, a3);
    auto p2 = __builtin_amdgcn_cvt_pkrtz(a4, a5);
    auto p3 = __builtin_amdgcn_cvt_pkrtz(a6, a7);
    int4 t; t.x = __builtin_bit_cast(int, p0); t.y = __builtin_bit_cast(int, p1);
            t.z = __builtin_bit_cast(int, p2); t.w = __builtin_bit_cast(int, p3);
    return __builtin_bit_cast(f16x8, t);
}

__device__ __forceinline__ float sigmoid_f(float x) {
    float e = __expf(-x);
    return __builtin_amdgcn_rcpf(1.0f + e);
}
__device__ __forceinline__ float tanh_f(float x) {
    float e = __expf(2.0f * x);               // overflow -> inf -> rcp -> 0 -> 1
    return 1.0f - 2.0f * __builtin_amdgcn_rcpf(e + 1.0f);
}

// ---------------- Phase 1: x-projection into fragment layout ----------------
template <int TC>
__global__ __launch_bounds__(256, 1)
void gru_xproj(const float* __restrict__ x,
               const float* __restrict__ w_ih,
               const float* __restrict__ b_ih,
               const float* __restrict__ b_hh,
               float* __restrict__ xp, int t0, int tlen)
{
    const int gb = blockIdx.y, g = gb >> 1, bt = gb & 1;
    const int tbase = t0 + blockIdx.x * TC;
    const int tid = threadIdx.x;
    const int w = tid >> 6, lw = tid & 63, p = lw >> 4, c = lw & 15;
    const int b_glob = bt * 16 + c;

    // A-frags: W_ih rows 64*mt + 16*w + c; k-map: k = 32*kt + 8*p + e
    f16x8 WI[3][2];
    #pragma unroll
    for (int mt = 0; mt < 3; ++mt) {
        const float* row = w_ih + ((size_t)g * K3_ + 64 * mt + 16 * w + c) * I_;
        #pragma unroll
        for (int kt = 0; kt < 2; ++kt) {
            const float4* p4 = reinterpret_cast<const float4*>(row + 32 * kt + 8 * p);
            float4 A = p4[0], Bq = p4[1];
            WI[mt][kt] = pack8(A.x, A.y, A.z, A.w, Bq.x, Bq.y, Bq.z, Bq.w);
        }
    }
    // Bias C-inits (C row-in-tile = 4p + r): r,z get b_ih+b_hh; n gets b_ih only
    f32x4 biasR, biasZ, biasN;
    #pragma unroll
    for (int r = 0; r < 4; ++r) {
        const int row = 16 * w + 4 * p + r;
        biasR[r] = b_ih[g * K3_ + row]        + b_hh[g * K3_ + row];
        biasZ[r] = b_ih[g * K3_ + 64 + row]   + b_hh[g * K3_ + 64 + row];
        biasN[r] = b_ih[g * K3_ + 128 + row];
    }

    const float* xb = x + ((size_t)b_glob * C_ + g * I_) * T_;   // + q*T_ + t
    float* xpo = xp + ((size_t)gb * tlen + (tbase - t0)) * XP_STRIDE + tid * 12;

    for (int tt = 0; tt < TC / 4; ++tt) {
        // Load x for this lane's 16 k-rows x 4 timesteps (full lines across tt)
        float xq[2][8][4];
        #pragma unroll
        for (int s = 0; s < 2; ++s)
            #pragma unroll
            for (int e = 0; e < 8; ++e) {
                const int q = 32 * s + 8 * p + e;
                float4 v = *reinterpret_cast<const float4*>(xb + (size_t)q * T_ + tbase + tt * 4);
                xq[s][e][0] = v.x; xq[s][e][1] = v.y; xq[s][e][2] = v.z; xq[s][e][3] = v.w;
            }
        #pragma unroll
        for (int tl = 0; tl < 4; ++tl) {
            f16x8 B0 = pack8(xq[0][0][tl], xq[0][1][tl], xq[0][2][tl], xq[0][3][tl],
                             xq[0][4][tl], xq[0][5][tl], xq[0][6][tl], xq[0][7][tl]);
            f16x8 B1 = pack8(xq[1][0][tl], xq[1][1][tl], xq[1][2][tl], xq[1][3][tl],
                             xq[1][4][tl], xq[1][5][tl], xq[1][6][tl], xq[1][7][tl]);
            f32x4 aR = mfma16(WI[0][0], B0, biasR); aR = mfma16(WI[0][1], B1, aR);
            f32x4 aZ = mfma16(WI[1][0], B0, biasZ); aZ = mfma16(WI[1][1], B1, aZ);
            f32x4 aN = mfma16(WI[2][0], B0, biasN); aN = mfma16(WI[2][1], B1, aN);
            float* o = xpo + (size_t)(tt * 4 + tl) * XP_STRIDE;
            *reinterpret_cast<float4*>(o + 0) = make_float4(aR[0], aR[1], aR[2], aR[3]);
            *reinterpret_cast<float4*>(o + 4) = make_float4(aZ[0], aZ[1], aZ[2], aZ[3]);
            *reinterpret_cast<float4*>(o + 8) = make_float4(aN[0], aN[1], aN[2], aN[3]);
        }
    }
}

// ---------------- Phase 2: MFMA scan ----------------
struct XPQ { f32x4 r, z, n; };
__device__ __forceinline__ XPQ ld_xp(const float* base, int tl) {
    const float4* p4 = reinterpret_cast<const float4*>(base + (size_t)tl * XP_STRIDE);
    float4 a = p4[0], b = p4[1], c = p4[2];
    XPQ q;
    q.r = f32x4{a.x, a.y, a.z, a.w};
    q.z = f32x4{b.x, b.y, b.z, b.w};
    q.n = f32x4{c.x, c.y, c.z, c.w};
    return q;
}

__global__ __launch_bounds__(256, 1)
void gru_scan_mfma(const float* __restrict__ xp,
                   const float* __restrict__ h0,
                   const float* __restrict__ w_hh,
                   const float* __restrict__ b_hh,
                   float* __restrict__ out,
                   float* __restrict__ h_state,
                   int t0, int tlen)
{
    const int gb = blockIdx.x, g = gb >> 1, bt = gb & 1;
    const int tid = threadIdx.x;
    const int w = tid >> 6, lw = tid & 63, p = lw >> 4, c = lw & 15;
    const int q0 = 16 * w + 4 * p;
    const int b_glob = bt * 16 + c;

    // h^T planes: halfidx(b=c, q) = c*64 + (q ^ ((c&7)<<3))
    __shared__ __align__(16) _Float16 h_lds[2][1024];

    // A-frags: W_hh rows 64*mt + 16*w + c, same k-map as phase 1
    f16x8 WH[3][2];
    #pragma unroll
    for (int mt = 0; mt < 3; ++mt) {
        const float* row = w_hh + ((size_t)g * K3_ + 64 * mt + 16 * w + c) * H_;
        #pragma unroll
        for (int kt = 0; kt < 2; ++kt) {
            const float4* p4 = reinterpret_cast<const float4*>(row + 32 * kt + 8 * p);
            float4 A = p4[0], Bq = p4[1];
            WH[mt][kt] = pack8(A.x, A.y, A.z, A.w, Bq.x, Bq.y, Bq.z, Bq.w);
        }
    }
    f32x4 BHN;   // n-gate C-init = b_hh n-rows
    #pragma unroll
    for (int r = 0; r < 4; ++r) BHN[r] = b_hh[g * K3_ + 128 + q0 + r];

    // h carry (f32, C layout) — from h0 on first chunk, else h_state
    float hC[4];
    if (t0 == 0) {
        #pragma unroll
        for (int r = 0; r < 4; ++r) hC[r] = h0[((size_t)g * B_ + b_glob) * H_ + q0 + r];
    } else {
        #pragma unroll
        for (int r = 0; r < 4; ++r) hC[r] = h_state[gb * 1024 + tid * 4 + r];
    }

    const int swz_w = c * 64 + (q0 ^ ((c & 7) << 3));               // write (4 halves)
    const int rb0 = c * 128 + 16 * ((p)     ^ (c & 7));             // B0 byte offset
    const int rb1 = c * 128 + 16 * ((4 + p) ^ (c & 7));             // B1 byte offset
    {
        f16x2 lo{(_Float16)hC[0], (_Float16)hC[1]};
        f16x2 hi{(_Float16)hC[2], (_Float16)hC[3]};
        int2 v; v.x = __builtin_bit_cast(int, lo); v.y = __builtin_bit_cast(int, hi);
        *reinterpret_cast<int2*>(reinterpret_cast<char*>(&h_lds[0][0]) + 2 * swz_w) = v;
    }

    float* outp = out + ((size_t)b_glob * C_ + g * 64 + q0) * T_;   // + r*T_ + t
    const float* xpl = xp + ((size_t)gb * tlen) * XP_STRIDE + tid * 12;

    float hist[4][FL_];   // 16-step output history (static indices only)

    // Prefetch depth 3
    XPQ cq0 = ld_xp(xpl, 0);
    XPQ cq1 = ld_xp(xpl, 1);
    XPQ cq2 = ld_xp(xpl, 2);
    __syncthreads();   // publish h_lds[0] (one-time full drain is fine)

    const int ngrp = tlen / FL_;
    for (int grp = 0; grp < ngrp; ++grp) {
        const int tg = grp * FL_;
        XPQ q[FL_ + 3];
        q[0] = cq0; q[1] = cq1; q[2] = cq2;

        #pragma unroll
        for (int u = 0; u < FL_; ++u) {
            // Prefetch xp for step tg+u+3 (clamped at chunk end)
            int tln = tg + u + 3; if (tln > tlen - 1) tln = tlen - 1;
            q[u + 3] = ld_xp(xpl, tln);

            const int rdbuf = u & 1;   // tg is even -> parity matches global t
            char* rbase = reinterpret_cast<char*>(&h_lds[rdbuf][0]);
            f16x8 B0 = *reinterpret_cast<const f16x8*>(rbase + rb0);
            f16x8 B1 = *reinterpret_cast<const f16x8*>(rbase + rb1);
            f32x4 aR = mfma16(WH[0][0], B0, q[u].r); aR = mfma16(WH[0][1], B1, aR);
            f32x4 aZ = mfma16(WH[1][0], B0, q[u].z); aZ = mfma16(WH[1][1], B1, aZ);
            f32x4 aN = mfma16(WH[2][0], B0, BHN);    aN = mfma16(WH[2][1], B1, aN);
            #pragma unroll
            for (int r = 0; r < 4; ++r) {
                float rr = sigmoid_f(aR[r]);
                float zz = sigmoid_f(aZ[r]);
                float nn = tanh_f(q[u].n[r] + rr * aN[r]);
                hC[r] = nn + zz * (hC[r] - nn);
                hist[r][u] = hC[r];
            }
            f16x2 lo{(_Float16)hC[0], (_Float16)hC[1]};
            f16x2 hi{(_Float16)hC[2], (_Float16)hC[3]};
            int2 v; v.x = __builtin_bit_cast(int, lo); v.y = __builtin_bit_cast(int, hi);
            *reinterpret_cast<int2*>(reinterpret_cast<char*>(&h_lds[rdbuf ^ 1][0]) + 2 * swz_w) = v;
            BARRIER_LGKM();   // LDS visibility only; loads/stores stay in flight
        }
        cq0 = q[FL_]; cq1 = q[FL_ + 1]; cq2 = q[FL_ + 2];

        // Coalesced flush: 4 rows x 4 dwordx4 = full 64B lines per row
        #pragma unroll
        for (int r = 0; r < 4; ++r) {
            float* po = outp + (size_t)r * T_ + (t0 + tg);
            *reinterpret_cast<float4*>(po + 0)  = make_float4(hist[r][0],  hist[r][1],  hist[r][2],  hist[r][3]);
            *reinterpret_cast<float4*>(po + 4)  = make_float4(hist[r][4],  hist[r][5],  hist[r][6],  hist[r][7]);
            *reinterpret_cast<float4*>(po + 8)  = make_float4(hist[r][8],  hist[r][9],  hist[r][10], hist[r][11]);
            *reinterpret_cast<float4*>(po + 12) = make_float4(hist[r][12], hist[r][13], hist[r][14], hist[r][15]);
        }
    }

    #pragma unroll
    for (int r = 0; r < 4; ++r) h_state[gb * 1024 + tid * 4 + r] = hC[r];
}

// ---------------- Host ----------------
extern "C" void kernel_launch(void* const* d_in, const int* in_sizes, int n_in,
                              void* d_out, int out_size, void* d_ws, size_t ws_size,
                              hipStream_t stream)
{
    const float* x    = (const float*)d_in[0];
    const float* h0   = (const float*)d_in[1];
    const float* w_ih = (const float*)d_in[2];
    const float* w_hh = (const float*)d_in[3];
    const float* b_ih = (const float*)d_in[4];
    const float* b_hh = (const float*)d_in[5];
    float* out = (float*)d_out;

    const size_t HSTATE_BYTES = 65536;
    // tlen: multiple of 16, divides 2000 -> {400, 80, 16}
    const int cand[3] = {400, 80, 16};
    int tlen = 16;
    for (int i = 0; i < 3; ++i) {
        size_t need = (size_t)cand[i] * GB_ * XP_STRIDE * 4 + HSTATE_BYTES;
        if (need <= ws_size) { tlen = cand[i]; break; }
    }
    const int TC = 16;
    float* xp = (float*)d_ws;
    float* h_state = (float*)((char*)d_ws + (size_t)tlen * GB_ * XP_STRIDE * 4);

    for (int t0 = 0; t0 < T_; t0 += tlen) {
        dim3 pg(tlen / TC, GB_);
        gru_xproj<16><<<pg, 256, 0, stream>>>(x, w_ih, b_ih, b_hh, xp, t0, tlen);
        gru_scan_mfma<<<GB_, 256, 0, stream>>>(xp, h0, w_hh, b_hh, out, h_state, t0, tlen);
    }
}

// Round 9
// 1184.959 us; speedup vs baseline: 1.8653x; 1.0251x over previous
//
#include <hip/hip_runtime.h>
#include <cstddef>
#include <cstdint>

// Grouped GRU via MFMA: B=32, C=512, T=2000, G=8, I=64, H=64
// Phase 1 (gru_xproj, all CUs): xp[t] = W_ih x_t + biases, f32, fragment layout.
// Phase 2 (gru_scan_mfma, 16 blocks): 6x mfma_f32_16x16x32_f16 per step.
// Round-9: fix the R8 register spill (VGPR=100 -> q[19]+hist[64] in scratch):
//   * xp prefetch = 4 rotating register slots (consume slot u&3, refill t+4),
//     macro-unrolled 8-step groups -> all indices compile-time.
//   * FL_=8: hist 32 f32; flush 2x dwordx4 per row (full 64B lines).

typedef _Float16 f16x8 __attribute__((ext_vector_type(8)));
typedef _Float16 f16x2 __attribute__((ext_vector_type(2)));
typedef float    f32x4 __attribute__((ext_vector_type(4)));

constexpr int B_ = 32, C_ = 512, T_ = 2000, G_ = 8, I_ = 64, H_ = 64, K3_ = 192;
constexpr int GB_ = 16;            // (g, bt) pairs
constexpr int XP_STRIDE = 3072;    // f32 per (gb, t): 192 rows x 16 batches
constexpr int FL_ = 8;             // flush group (steps held in registers)

// LDS-visibility barrier WITHOUT vmcnt drain (global stores/prefetch stay in flight)
#define BARRIER_LGKM() asm volatile("s_waitcnt lgkmcnt(0)\n\ts_barrier" ::: "memory")

__device__ __forceinline__ f32x4 mfma16(f16x8 a, f16x8 b, f32x4 c) {
    return __builtin_amdgcn_mfma_f32_16x16x32_f16(a, b, c, 0, 0, 0);
}

__device__ __forceinline__ f16x8 pack8(float a0,float a1,float a2,float a3,
                                       float a4,float a5,float a6,float a7) {
    auto p0 = __builtin_amdgcn_cvt_pkrtz(a0, a1);   // __fp16x2, 4 bytes
    auto p1 = __builtin_amdgcn_cvt_pkrtz(a2, a3);
    auto p2 = __builtin_amdgcn_cvt_pkrtz(a4, a5);
    auto p3 = __builtin_amdgcn_cvt_pkrtz(a6, a7);
    int4 t; t.x = __builtin_bit_cast(int, p0); t.y = __builtin_bit_cast(int, p1);
            t.z = __builtin_bit_cast(int, p2); t.w = __builtin_bit_cast(int, p3);
    return __builtin_bit_cast(f16x8, t);
}

__device__ __forceinline__ float sigmoid_f(float x) {
    float e = __expf(-x);
    return __builtin_amdgcn_rcpf(1.0f + e);
}
__device__ __forceinline__ float tanh_f(float x) {
    float e = __expf(2.0f * x);               // overflow -> inf -> rcp -> 0 -> 1
    return 1.0f - 2.0f * __builtin_amdgcn_rcpf(e + 1.0f);
}

// ---------------- Phase 1: x-projection into fragment layout ----------------
template <int TC>
__global__ __launch_bounds__(256, 1)
void gru_xproj(const float* __restrict__ x,
               const float* __restrict__ w_ih,
               const float* __restrict__ b_ih,
               const float* __restrict__ b_hh,
               float* __restrict__ xp, int t0, int tlen)
{
    const int gb = blockIdx.y, g = gb >> 1, bt = gb & 1;
    const int tbase = t0 + blockIdx.x * TC;
    const int tid = threadIdx.x;
    const int w = tid >> 6, lw = tid & 63, p = lw >> 4, c = lw & 15;
    const int b_glob = bt * 16 + c;

    // A-frags: W_ih rows 64*mt + 16*w + c; k-map: k = 32*kt + 8*p + e
    f16x8 WI[3][2];
    #pragma unroll
    for (int mt = 0; mt < 3; ++mt) {
        const float* row = w_ih + ((size_t)g * K3_ + 64 * mt + 16 * w + c) * I_;
        #pragma unroll
        for (int kt = 0; kt < 2; ++kt) {
            const float4* p4 = reinterpret_cast<const float4*>(row + 32 * kt + 8 * p);
            float4 A = p4[0], Bq = p4[1];
            WI[mt][kt] = pack8(A.x, A.y, A.z, A.w, Bq.x, Bq.y, Bq.z, Bq.w);
        }
    }
    // Bias C-inits (C row-in-tile = 4p + r): r,z get b_ih+b_hh; n gets b_ih only
    f32x4 biasR, biasZ, biasN;
    #pragma unroll
    for (int r = 0; r < 4; ++r) {
        const int row = 16 * w + 4 * p + r;
        biasR[r] = b_ih[g * K3_ + row]        + b_hh[g * K3_ + row];
        biasZ[r] = b_ih[g * K3_ + 64 + row]   + b_hh[g * K3_ + 64 + row];
        biasN[r] = b_ih[g * K3_ + 128 + row];
    }

    const float* xb = x + ((size_t)b_glob * C_ + g * I_) * T_;   // + q*T_ + t
    float* xpo = xp + ((size_t)gb * tlen + (tbase - t0)) * XP_STRIDE + tid * 12;

    for (int tt = 0; tt < TC / 4; ++tt) {
        float xq[2][8][4];
        #pragma unroll
        for (int s = 0; s < 2; ++s)
            #pragma unroll
            for (int e = 0; e < 8; ++e) {
                const int q = 32 * s + 8 * p + e;
                float4 v = *reinterpret_cast<const float4*>(xb + (size_t)q * T_ + tbase + tt * 4);
                xq[s][e][0] = v.x; xq[s][e][1] = v.y; xq[s][e][2] = v.z; xq[s][e][3] = v.w;
            }
        #pragma unroll
        for (int tl = 0; tl < 4; ++tl) {
            f16x8 B0 = pack8(xq[0][0][tl], xq[0][1][tl], xq[0][2][tl], xq[0][3][tl],
                             xq[0][4][tl], xq[0][5][tl], xq[0][6][tl], xq[0][7][tl]);
            f16x8 B1 = pack8(xq[1][0][tl], xq[1][1][tl], xq[1][2][tl], xq[1][3][tl],
                             xq[1][4][tl], xq[1][5][tl], xq[1][6][tl], xq[1][7][tl]);
            f32x4 aR = mfma16(WI[0][0], B0, biasR); aR = mfma16(WI[0][1], B1, aR);
            f32x4 aZ = mfma16(WI[1][0], B0, biasZ); aZ = mfma16(WI[1][1], B1, aZ);
            f32x4 aN = mfma16(WI[2][0], B0, biasN); aN = mfma16(WI[2][1], B1, aN);
            float* o = xpo + (size_t)(tt * 4 + tl) * XP_STRIDE;
            *reinterpret_cast<float4*>(o + 0) = make_float4(aR[0], aR[1], aR[2], aR[3]);
            *reinterpret_cast<float4*>(o + 4) = make_float4(aZ[0], aZ[1], aZ[2], aZ[3]);
            *reinterpret_cast<float4*>(o + 8) = make_float4(aN[0], aN[1], aN[2], aN[3]);
        }
    }
}

// ---------------- Phase 2: MFMA scan ----------------
struct XPQ { f32x4 r, z, n; };
__device__ __forceinline__ XPQ ld_xp(const float* base, int tl) {
    const float4* p4 = reinterpret_cast<const float4*>(base + (size_t)tl * XP_STRIDE);
    float4 a = p4[0], b = p4[1], c = p4[2];
    XPQ q;
    q.r = f32x4{a.x, a.y, a.z, a.w};
    q.z = f32x4{b.x, b.y, b.z, b.w};
    q.n = f32x4{c.x, c.y, c.z, c.w};
    return q;
}

__global__ __launch_bounds__(256, 1)
void gru_scan_mfma(const float* __restrict__ xp,
                   const float* __restrict__ h0,
                   const float* __restrict__ w_hh,
                   const float* __restrict__ b_hh,
                   float* __restrict__ out,
                   float* __restrict__ h_state,
                   int t0, int tlen)
{
    const int gb = blockIdx.x, g = gb >> 1, bt = gb & 1;
    const int tid = threadIdx.x;
    const int w = tid >> 6, lw = tid & 63, p = lw >> 4, c = lw & 15;
    const int q0 = 16 * w + 4 * p;
    const int b_glob = bt * 16 + c;

    // h^T planes: halfidx(b=c, q) = c*64 + (q ^ ((c&7)<<3))
    __shared__ __align__(16) _Float16 h_lds[2][1024];

    // A-frags: W_hh rows 64*mt + 16*w + c, same k-map as phase 1
    f16x8 WH[3][2];
    #pragma unroll
    for (int mt = 0; mt < 3; ++mt) {
        const float* row = w_hh + ((size_t)g * K3_ + 64 * mt + 16 * w + c) * H_;
        #pragma unroll
        for (int kt = 0; kt < 2; ++kt) {
            const float4* p4 = reinterpret_cast<const float4*>(row + 32 * kt + 8 * p);
            float4 A = p4[0], Bq = p4[1];
            WH[mt][kt] = pack8(A.x, A.y, A.z, A.w, Bq.x, Bq.y, Bq.z, Bq.w);
        }
    }
    f32x4 BHN;   // n-gate C-init = b_hh n-rows
    #pragma unroll
    for (int r = 0; r < 4; ++r) BHN[r] = b_hh[g * K3_ + 128 + q0 + r];

    // h carry (f32, C layout) — from h0 on first chunk, else h_state
    float hC[4];
    if (t0 == 0) {
        #pragma unroll
        for (int r = 0; r < 4; ++r) hC[r] = h0[((size_t)g * B_ + b_glob) * H_ + q0 + r];
    } else {
        #pragma unroll
        for (int r = 0; r < 4; ++r) hC[r] = h_state[gb * 1024 + tid * 4 + r];
    }

    const int swz_w = c * 64 + (q0 ^ ((c & 7) << 3));               // write (4 halves)
    const int rb0 = c * 128 + 16 * ((p)     ^ (c & 7));             // B0 byte offset
    const int rb1 = c * 128 + 16 * ((4 + p) ^ (c & 7));             // B1 byte offset
    {
        f16x2 lo{(_Float16)hC[0], (_Float16)hC[1]};
        f16x2 hi{(_Float16)hC[2], (_Float16)hC[3]};
        int2 v; v.x = __builtin_bit_cast(int, lo); v.y = __builtin_bit_cast(int, hi);
        *reinterpret_cast<int2*>(reinterpret_cast<char*>(&h_lds[0][0]) + 2 * swz_w) = v;
    }

    float* outp = out + ((size_t)b_glob * C_ + g * 64 + q0) * T_;   // + r*T_ + t
    const float* xpl = xp + ((size_t)gb * tlen) * XP_STRIDE + tid * 12;

    float hist[4][FL_];   // 8-step output history (static indices, 32 f32)

    // 4 rotating prefetch slots (48 f32 total live)
    XPQ qs[4];
    qs[0] = ld_xp(xpl, 0);
    qs[1] = ld_xp(xpl, 1);
    qs[2] = ld_xp(xpl, 2);
    qs[3] = ld_xp(xpl, 3);
    __syncthreads();   // publish h_lds[0] (one-time full drain is fine)

    // One scan step: consume slot S (= u&3), then refill S with xp[tg+u+4].
    #define STEP_U(U) do {                                                        \
        const int S = (U) & 3;                                                    \
        const int rdbuf = (U) & 1;                                                \
        char* rbase = reinterpret_cast<char*>(&h_lds[rdbuf][0]);                  \
        f16x8 B0 = *reinterpret_cast<const f16x8*>(rbase + rb0);                  \
        f16x8 B1 = *reinterpret_cast<const f16x8*>(rbase + rb1);                  \
        f32x4 aR = mfma16(WH[0][0], B0, qs[S].r); aR = mfma16(WH[0][1], B1, aR);  \
        f32x4 aZ = mfma16(WH[1][0], B0, qs[S].z); aZ = mfma16(WH[1][1], B1, aZ);  \
        f32x4 aN = mfma16(WH[2][0], B0, BHN);     aN = mfma16(WH[2][1], B1, aN);  \
        f32x4 xn = qs[S].n;                                                       \
        int tln = tg + (U) + 4; if (tln > tlen - 1) tln = tlen - 1;               \
        qs[S] = ld_xp(xpl, tln);  /* refill for step tg+U+4 */                    \
        _Pragma("unroll")                                                         \
        for (int r = 0; r < 4; ++r) {                                             \
            float rr = sigmoid_f(aR[r]);                                          \
            float zz = sigmoid_f(aZ[r]);                                          \
            float nn = tanh_f(xn[r] + rr * aN[r]);                                \
            hC[r] = nn + zz * (hC[r] - nn);                                       \
            hist[r][U] = hC[r];                                                   \
        }                                                                         \
        f16x2 lo{(_Float16)hC[0], (_Float16)hC[1]};                               \
        f16x2 hi{(_Float16)hC[2], (_Float16)hC[3]};                               \
        int2 v; v.x = __builtin_bit_cast(int, lo); v.y = __builtin_bit_cast(int, hi); \
        *reinterpret_cast<int2*>(reinterpret_cast<char*>(&h_lds[rdbuf ^ 1][0]) + 2 * swz_w) = v; \
        BARRIER_LGKM();                                                           \
    } while (0)

    const int ngrp = tlen / FL_;
    for (int grp = 0; grp < ngrp; ++grp) {
        const int tg = grp * FL_;
        STEP_U(0); STEP_U(1); STEP_U(2); STEP_U(3);
        STEP_U(4); STEP_U(5); STEP_U(6); STEP_U(7);

        // Coalesced flush: 4 rows x 2 dwordx4 (full 64B lines per row-pair)
        #pragma unroll
        for (int r = 0; r < 4; ++r) {
            float* po = outp + (size_t)r * T_ + (t0 + tg);
            *reinterpret_cast<float4*>(po + 0) = make_float4(hist[r][0], hist[r][1], hist[r][2], hist[r][3]);
            *reinterpret_cast<float4*>(po + 4) = make_float4(hist[r][4], hist[r][5], hist[r][6], hist[r][7]);
        }
    }
    #undef STEP_U

    #pragma unroll
    for (int r = 0; r < 4; ++r) h_state[gb * 1024 + tid * 4 + r] = hC[r];
}

// ---------------- Host ----------------
extern "C" void kernel_launch(void* const* d_in, const int* in_sizes, int n_in,
                              void* d_out, int out_size, void* d_ws, size_t ws_size,
                              hipStream_t stream)
{
    const float* x    = (const float*)d_in[0];
    const float* h0   = (const float*)d_in[1];
    const float* w_ih = (const float*)d_in[2];
    const float* w_hh = (const float*)d_in[3];
    const float* b_ih = (const float*)d_in[4];
    const float* b_hh = (const float*)d_in[5];
    float* out = (float*)d_out;

    const size_t HSTATE_BYTES = 65536;
    // tlen: multiple of 8, divides 2000 -> {400, 200, 40, 8}
    const int cand[4] = {400, 200, 40, 8};
    int tlen = 8;
    for (int i = 0; i < 4; ++i) {
        size_t need = (size_t)cand[i] * GB_ * XP_STRIDE * 4 + HSTATE_BYTES;
        if (need <= ws_size) { tlen = cand[i]; break; }
    }
    const int TC = 8;
    float* xp = (float*)d_ws;
    float* h_state = (float*)((char*)d_ws + (size_t)tlen * GB_ * XP_STRIDE * 4);

    for (int t0 = 0; t0 < T_; t0 += tlen) {
        dim3 pg(tlen / TC, GB_);
        gru_xproj<8><<<pg, 256, 0, stream>>>(x, w_ih, b_ih, b_hh, xp, t0, tlen);
        gru_scan_mfma<<<GB_, 256, 0, stream>>>(xp, h0, w_hh, b_hh, out, h_state, t0, tlen);
    }
}